// Round 1
// baseline (838.161 us; speedup 1.0000x reference)
//
#include <hip/hip_runtime.h>

// GraphSNN: per-node MLP (13->16->8->8, relu each layer) -> segment_sum over
// dag ids (20k dags) -> per-dag MLP (8->16->8->8, relu each layer) -> sum.
// Output: [num_dags*8] dag_summ ++ [8] global_summ, fp32.

extern "C" __global__ void __launch_bounds__(256) gsnn_node_kernel(
    const float* __restrict__ inputs,
    const int*   __restrict__ node_to_dag,
    const float* __restrict__ w0, const float* __restrict__ b0,
    const float* __restrict__ w1, const float* __restrict__ b1,
    const float* __restrict__ w2, const float* __restrict__ b2,
    float* __restrict__ dag_out,
    int n_nodes)
{
    // Weights staged to LDS, read as broadcast float4 (uniform addr -> 1 instr/wave)
    __shared__ float4 w0s[52];   // [13][16] row-major as [k*4 + j4]
    __shared__ float4 b0s[4];
    __shared__ float4 w1s[32];   // [16][8]  row-major as [k*2 + j4]
    __shared__ float4 b1s[2];
    __shared__ float4 w2s[16];   // [8][8]   row-major as [k*2 + j4]
    __shared__ float4 b2s[2];

    const int tid = threadIdx.x;
    {
        float* p;
        p = (float*)w0s; for (int i = tid; i < 208; i += 256) p[i] = w0[i];
        p = (float*)w1s; for (int i = tid; i < 128; i += 256) p[i] = w1[i];
        p = (float*)w2s; if (tid < 64) p[tid] = w2[tid];
        p = (float*)b0s; if (tid < 16) p[tid] = b0[tid];
        p = (float*)b1s; if (tid < 8)  p[tid] = b1[tid];
        p = (float*)b2s; if (tid < 8)  p[tid] = b2[tid];
    }
    __syncthreads();

    const long long t    = (long long)blockIdx.x * 256 + tid;
    const long long base = t * 4;                  // 4 nodes per thread
    if (base >= (long long)n_nodes) return;

    float xs[52];   // xs[n*13 + k]
    int   dg[4];
    int   nvalid;
    if (base + 4 <= (long long)n_nodes) {
        nvalid = 4;
        // 52 floats for 4 consecutive nodes: 13 aligned float4 loads (52*n % 4 == 0)
        const float4* in4 = (const float4*)(inputs + base * 13);
        #pragma unroll
        for (int i = 0; i < 13; ++i) {
            const float4 v = in4[i];
            xs[i*4+0] = v.x; xs[i*4+1] = v.y; xs[i*4+2] = v.z; xs[i*4+3] = v.w;
        }
        const int4 dd = *(const int4*)(node_to_dag + base);
        dg[0] = dd.x; dg[1] = dd.y; dg[2] = dd.z; dg[3] = dd.w;
    } else {
        nvalid = (int)((long long)n_nodes - base);
        #pragma unroll
        for (int n = 0; n < 4; ++n) {
            if (n < nvalid) {
                #pragma unroll
                for (int k = 0; k < 13; ++k) xs[n*13+k] = inputs[(base + n)*13 + k];
                dg[n] = node_to_dag[base + n];
            } else {
                #pragma unroll
                for (int k = 0; k < 13; ++k) xs[n*13+k] = 0.f;
                dg[n] = 0;
            }
        }
    }

    // ---- layer 0: 13 -> 16, relu ----
    float h0[64];   // h0[n*16 + j]
    #pragma unroll
    for (int j4 = 0; j4 < 4; ++j4) {
        const float4 b = b0s[j4];
        #pragma unroll
        for (int n = 0; n < 4; ++n) {
            h0[n*16 + j4*4 + 0] = b.x;
            h0[n*16 + j4*4 + 1] = b.y;
            h0[n*16 + j4*4 + 2] = b.z;
            h0[n*16 + j4*4 + 3] = b.w;
        }
    }
    #pragma unroll
    for (int k = 0; k < 13; ++k) {
        #pragma unroll
        for (int j4 = 0; j4 < 4; ++j4) {
            const float4 w = w0s[k*4 + j4];
            #pragma unroll
            for (int n = 0; n < 4; ++n) {
                const float x = xs[n*13 + k];
                h0[n*16 + j4*4 + 0] = fmaf(x, w.x, h0[n*16 + j4*4 + 0]);
                h0[n*16 + j4*4 + 1] = fmaf(x, w.y, h0[n*16 + j4*4 + 1]);
                h0[n*16 + j4*4 + 2] = fmaf(x, w.z, h0[n*16 + j4*4 + 2]);
                h0[n*16 + j4*4 + 3] = fmaf(x, w.w, h0[n*16 + j4*4 + 3]);
            }
        }
    }
    #pragma unroll
    for (int i = 0; i < 64; ++i) h0[i] = fmaxf(h0[i], 0.f);

    // ---- layer 1: 16 -> 8, relu ----
    float h1[32];   // h1[n*8 + j]
    #pragma unroll
    for (int j4 = 0; j4 < 2; ++j4) {
        const float4 b = b1s[j4];
        #pragma unroll
        for (int n = 0; n < 4; ++n) {
            h1[n*8 + j4*4 + 0] = b.x;
            h1[n*8 + j4*4 + 1] = b.y;
            h1[n*8 + j4*4 + 2] = b.z;
            h1[n*8 + j4*4 + 3] = b.w;
        }
    }
    #pragma unroll
    for (int k = 0; k < 16; ++k) {
        #pragma unroll
        for (int j4 = 0; j4 < 2; ++j4) {
            const float4 w = w1s[k*2 + j4];
            #pragma unroll
            for (int n = 0; n < 4; ++n) {
                const float x = h0[n*16 + k];
                h1[n*8 + j4*4 + 0] = fmaf(x, w.x, h1[n*8 + j4*4 + 0]);
                h1[n*8 + j4*4 + 1] = fmaf(x, w.y, h1[n*8 + j4*4 + 1]);
                h1[n*8 + j4*4 + 2] = fmaf(x, w.z, h1[n*8 + j4*4 + 2]);
                h1[n*8 + j4*4 + 3] = fmaf(x, w.w, h1[n*8 + j4*4 + 3]);
            }
        }
    }
    #pragma unroll
    for (int i = 0; i < 32; ++i) h1[i] = fmaxf(h1[i], 0.f);

    // ---- layer 2: 8 -> 8, relu ----
    float h2[32];   // h2[n*8 + j]
    #pragma unroll
    for (int j4 = 0; j4 < 2; ++j4) {
        const float4 b = b2s[j4];
        #pragma unroll
        for (int n = 0; n < 4; ++n) {
            h2[n*8 + j4*4 + 0] = b.x;
            h2[n*8 + j4*4 + 1] = b.y;
            h2[n*8 + j4*4 + 2] = b.z;
            h2[n*8 + j4*4 + 3] = b.w;
        }
    }
    #pragma unroll
    for (int k = 0; k < 8; ++k) {
        #pragma unroll
        for (int j4 = 0; j4 < 2; ++j4) {
            const float4 w = w2s[k*2 + j4];
            #pragma unroll
            for (int n = 0; n < 4; ++n) {
                const float x = h1[n*8 + k];
                h2[n*8 + j4*4 + 0] = fmaf(x, w.x, h2[n*8 + j4*4 + 0]);
                h2[n*8 + j4*4 + 1] = fmaf(x, w.y, h2[n*8 + j4*4 + 1]);
                h2[n*8 + j4*4 + 2] = fmaf(x, w.z, h2[n*8 + j4*4 + 2]);
                h2[n*8 + j4*4 + 3] = fmaf(x, w.w, h2[n*8 + j4*4 + 3]);
            }
        }
    }
    #pragma unroll
    for (int i = 0; i < 32; ++i) h2[i] = fmaxf(h2[i], 0.f);

    // ---- scatter: segment sum via device-scope atomics ----
    #pragma unroll
    for (int n = 0; n < 4; ++n) {
        if (n < nvalid) {
            float* dst = dag_out + (long long)dg[n] * 8;
            #pragma unroll
            for (int j = 0; j < 8; ++j) atomicAdd(dst + j, h2[n*8 + j]);
        }
    }
}

extern "C" __global__ void __launch_bounds__(256) gsnn_dag_kernel(
    const float* __restrict__ dag_summ,
    const float* __restrict__ w0, const float* __restrict__ b0,
    const float* __restrict__ w1, const float* __restrict__ b1,
    const float* __restrict__ w2, const float* __restrict__ b2,
    float* __restrict__ global_out,
    int num_dags)
{
    __shared__ float4 w0s[32];   // [8][16] as [k*4 + j4]
    __shared__ float4 b0s[4];
    __shared__ float4 w1s[32];   // [16][8] as [k*2 + j4]
    __shared__ float4 b1s[2];
    __shared__ float4 w2s[16];   // [8][8]  as [k*2 + j4]
    __shared__ float4 b2s[2];
    __shared__ float  gsum_s[8];

    const int tid = threadIdx.x;
    {
        float* p;
        p = (float*)w0s; for (int i = tid; i < 128; i += 256) p[i] = w0[i];
        p = (float*)w1s; for (int i = tid; i < 128; i += 256) p[i] = w1[i];
        p = (float*)w2s; if (tid < 64) p[tid] = w2[tid];
        p = (float*)b0s; if (tid < 16) p[tid] = b0[tid];
        p = (float*)b1s; if (tid < 8)  p[tid] = b1[tid];
        p = (float*)b2s; if (tid < 8)  p[tid] = b2[tid];
    }
    if (tid < 8) gsum_s[tid] = 0.f;
    __syncthreads();

    const int d = blockIdx.x * 256 + tid;

    float h2[8] = {0.f, 0.f, 0.f, 0.f, 0.f, 0.f, 0.f, 0.f};
    if (d < num_dags) {
        float x[8];
        const float4* r4 = (const float4*)(dag_summ + (long long)d * 8);
        {
            const float4 a = r4[0], b = r4[1];
            x[0]=a.x; x[1]=a.y; x[2]=a.z; x[3]=a.w;
            x[4]=b.x; x[5]=b.y; x[6]=b.z; x[7]=b.w;
        }
        float h0[16];
        #pragma unroll
        for (int j4 = 0; j4 < 4; ++j4) {
            const float4 b = b0s[j4];
            h0[j4*4+0]=b.x; h0[j4*4+1]=b.y; h0[j4*4+2]=b.z; h0[j4*4+3]=b.w;
        }
        #pragma unroll
        for (int k = 0; k < 8; ++k) {
            #pragma unroll
            for (int j4 = 0; j4 < 4; ++j4) {
                const float4 w = w0s[k*4 + j4];
                h0[j4*4+0] = fmaf(x[k], w.x, h0[j4*4+0]);
                h0[j4*4+1] = fmaf(x[k], w.y, h0[j4*4+1]);
                h0[j4*4+2] = fmaf(x[k], w.z, h0[j4*4+2]);
                h0[j4*4+3] = fmaf(x[k], w.w, h0[j4*4+3]);
            }
        }
        #pragma unroll
        for (int i = 0; i < 16; ++i) h0[i] = fmaxf(h0[i], 0.f);

        float h1[8];
        #pragma unroll
        for (int j4 = 0; j4 < 2; ++j4) {
            const float4 b = b1s[j4];
            h1[j4*4+0]=b.x; h1[j4*4+1]=b.y; h1[j4*4+2]=b.z; h1[j4*4+3]=b.w;
        }
        #pragma unroll
        for (int k = 0; k < 16; ++k) {
            #pragma unroll
            for (int j4 = 0; j4 < 2; ++j4) {
                const float4 w = w1s[k*2 + j4];
                h1[j4*4+0] = fmaf(h0[k], w.x, h1[j4*4+0]);
                h1[j4*4+1] = fmaf(h0[k], w.y, h1[j4*4+1]);
                h1[j4*4+2] = fmaf(h0[k], w.z, h1[j4*4+2]);
                h1[j4*4+3] = fmaf(h0[k], w.w, h1[j4*4+3]);
            }
        }
        #pragma unroll
        for (int i = 0; i < 8; ++i) h1[i] = fmaxf(h1[i], 0.f);

        #pragma unroll
        for (int j4 = 0; j4 < 2; ++j4) {
            const float4 b = b2s[j4];
            h2[j4*4+0]=b.x; h2[j4*4+1]=b.y; h2[j4*4+2]=b.z; h2[j4*4+3]=b.w;
        }
        #pragma unroll
        for (int k = 0; k < 8; ++k) {
            #pragma unroll
            for (int j4 = 0; j4 < 2; ++j4) {
                const float4 w = w2s[k*2 + j4];
                h2[j4*4+0] = fmaf(h1[k], w.x, h2[j4*4+0]);
                h2[j4*4+1] = fmaf(h1[k], w.y, h2[j4*4+1]);
                h2[j4*4+2] = fmaf(h1[k], w.z, h2[j4*4+2]);
                h2[j4*4+3] = fmaf(h1[k], w.w, h2[j4*4+3]);
            }
        }
        #pragma unroll
        for (int i = 0; i < 8; ++i) h2[i] = fmaxf(h2[i], 0.f);
    }

    // wave(64) reduce each of the 8 outputs, then LDS, then global atomics
    #pragma unroll
    for (int j = 0; j < 8; ++j) {
        float v = h2[j];
        for (int off = 32; off > 0; off >>= 1) v += __shfl_down(v, off);
        if ((tid & 63) == 0) atomicAdd(&gsum_s[j], v);
    }
    __syncthreads();
    if (tid < 8) atomicAdd(global_out + tid, gsum_s[tid]);
}

extern "C" void kernel_launch(void* const* d_in, const int* in_sizes, int n_in,
                              void* d_out, int out_size, void* d_ws, size_t ws_size,
                              hipStream_t stream) {
    const float* inputs      = (const float*)d_in[0];
    const int*   node_to_dag = (const int*)  d_in[1];
    // d_in[2] = num_dags (scalar); derived from out_size instead.
    const float* dw0 = (const float*)d_in[3];
    const float* db0 = (const float*)d_in[4];
    const float* dw1 = (const float*)d_in[5];
    const float* db1 = (const float*)d_in[6];
    const float* dw2 = (const float*)d_in[7];
    const float* db2 = (const float*)d_in[8];
    const float* gw0 = (const float*)d_in[9];
    const float* gb0 = (const float*)d_in[10];
    const float* gw1 = (const float*)d_in[11];
    const float* gb1 = (const float*)d_in[12];
    const float* gw2 = (const float*)d_in[13];
    const float* gb2 = (const float*)d_in[14];

    float* out = (float*)d_out;
    const int num_dags = (out_size - 8) / 8;
    const int n_nodes  = in_sizes[0] / 13;

    // zero both outputs (atomically accumulated into)
    hipMemsetAsync(d_out, 0, (size_t)out_size * sizeof(float), stream);

    const int threads_needed = (n_nodes + 3) / 4;
    const int blocks1 = (threads_needed + 255) / 256;
    gsnn_node_kernel<<<blocks1, 256, 0, stream>>>(
        inputs, node_to_dag, dw0, db0, dw1, db1, dw2, db2, out, n_nodes);

    const int blocks2 = (num_dags + 255) / 256;
    gsnn_dag_kernel<<<blocks2, 256, 0, stream>>>(
        out, gw0, gb0, gw1, gb1, gw2, gb2, out + (size_t)num_dags * 8, num_dags);
}

// Round 2
// 160.564 us; speedup vs baseline: 5.2201x; 5.2201x over previous
//
#include <hip/hip_runtime.h>

// GraphSNN: per-node MLP (13->16->8->8, relu each layer) -> segment_sum over
// dag ids (20k dags) -> per-dag MLP (8->16->8->8, relu each layer) -> sum.
// Output: [num_dags*8] dag_summ ++ [8] global_summ, fp32.
//
// Round 2: kill the 16M device-scope fp32 atomics (WRITE_SIZE was 500 MB,
// atomic-throughput bound at 838 us). New plan:
//   K1 node_mlp:    inputs -> s[N][8] in ws               (no atomics)
//   K2 seg_partial: dag-range-partitioned LDS accumulation, partials -> ws
//                   (LDS atomics only)
//   K3 dag_finish:  sum partials -> dag_summ, dag MLP, global sum
//                   (632 global atomics total)

#define DPP    4000   // dags per partition: 4000*8*4B = 128 KB LDS
#define NCHUNK 51     // node chunks per partition; 5*51 = 255 blocks (1/CU)

// ---------------------------------------------------------------- K1
extern "C" __global__ void __launch_bounds__(256) gsnn_node_mlp(
    const float* __restrict__ inputs,
    const float* __restrict__ w0, const float* __restrict__ b0,
    const float* __restrict__ w1, const float* __restrict__ b1,
    const float* __restrict__ w2, const float* __restrict__ b2,
    float* __restrict__ s_out,
    int n_nodes)
{
    __shared__ float4 w0s[52];   // [13][16] as [k*4 + j4]
    __shared__ float4 b0s[4];
    __shared__ float4 w1s[32];   // [16][8]  as [k*2 + j4]
    __shared__ float4 b1s[2];
    __shared__ float4 w2s[16];   // [8][8]   as [k*2 + j4]
    __shared__ float4 b2s[2];

    const int tid = threadIdx.x;
    {
        float* p;
        p = (float*)w0s; for (int i = tid; i < 208; i += 256) p[i] = w0[i];
        p = (float*)w1s; for (int i = tid; i < 128; i += 256) p[i] = w1[i];
        p = (float*)w2s; if (tid < 64) p[tid] = w2[tid];
        p = (float*)b0s; if (tid < 16) p[tid] = b0[tid];
        p = (float*)b1s; if (tid < 8)  p[tid] = b1[tid];
        p = (float*)b2s; if (tid < 8)  p[tid] = b2[tid];
    }
    __syncthreads();

    const long long t    = (long long)blockIdx.x * 256 + tid;
    const long long base = t * 4;                  // 4 nodes per thread
    if (base >= (long long)n_nodes) return;

    float xs[52];   // xs[n*13 + k] via 13 aligned float4 loads
    int   nvalid;
    if (base + 4 <= (long long)n_nodes) {
        nvalid = 4;
        const float4* in4 = (const float4*)(inputs + base * 13);
        #pragma unroll
        for (int i = 0; i < 13; ++i) {
            const float4 v = in4[i];
            xs[i*4+0] = v.x; xs[i*4+1] = v.y; xs[i*4+2] = v.z; xs[i*4+3] = v.w;
        }
    } else {
        nvalid = (int)((long long)n_nodes - base);
        #pragma unroll
        for (int n = 0; n < 4; ++n) {
            #pragma unroll
            for (int k = 0; k < 13; ++k)
                xs[n*13+k] = (n < nvalid) ? inputs[(base + n)*13 + k] : 0.f;
        }
    }

    // process the 4 nodes sequentially to keep VGPR pressure low
    #pragma unroll
    for (int n = 0; n < 4; ++n) {
        if (n >= nvalid) break;
        float h0[16];
        #pragma unroll
        for (int j4 = 0; j4 < 4; ++j4) {
            const float4 b = b0s[j4];
            h0[j4*4+0]=b.x; h0[j4*4+1]=b.y; h0[j4*4+2]=b.z; h0[j4*4+3]=b.w;
        }
        #pragma unroll
        for (int k = 0; k < 13; ++k) {
            const float x = xs[n*13 + k];
            #pragma unroll
            for (int j4 = 0; j4 < 4; ++j4) {
                const float4 w = w0s[k*4 + j4];
                h0[j4*4+0] = fmaf(x, w.x, h0[j4*4+0]);
                h0[j4*4+1] = fmaf(x, w.y, h0[j4*4+1]);
                h0[j4*4+2] = fmaf(x, w.z, h0[j4*4+2]);
                h0[j4*4+3] = fmaf(x, w.w, h0[j4*4+3]);
            }
        }
        #pragma unroll
        for (int i = 0; i < 16; ++i) h0[i] = fmaxf(h0[i], 0.f);

        float h1[8];
        #pragma unroll
        for (int j4 = 0; j4 < 2; ++j4) {
            const float4 b = b1s[j4];
            h1[j4*4+0]=b.x; h1[j4*4+1]=b.y; h1[j4*4+2]=b.z; h1[j4*4+3]=b.w;
        }
        #pragma unroll
        for (int k = 0; k < 16; ++k) {
            const float x = h0[k];
            #pragma unroll
            for (int j4 = 0; j4 < 2; ++j4) {
                const float4 w = w1s[k*2 + j4];
                h1[j4*4+0] = fmaf(x, w.x, h1[j4*4+0]);
                h1[j4*4+1] = fmaf(x, w.y, h1[j4*4+1]);
                h1[j4*4+2] = fmaf(x, w.z, h1[j4*4+2]);
                h1[j4*4+3] = fmaf(x, w.w, h1[j4*4+3]);
            }
        }
        #pragma unroll
        for (int i = 0; i < 8; ++i) h1[i] = fmaxf(h1[i], 0.f);

        float h2[8];
        #pragma unroll
        for (int j4 = 0; j4 < 2; ++j4) {
            const float4 b = b2s[j4];
            h2[j4*4+0]=b.x; h2[j4*4+1]=b.y; h2[j4*4+2]=b.z; h2[j4*4+3]=b.w;
        }
        #pragma unroll
        for (int k = 0; k < 8; ++k) {
            const float x = h1[k];
            #pragma unroll
            for (int j4 = 0; j4 < 2; ++j4) {
                const float4 w = w2s[k*2 + j4];
                h2[j4*4+0] = fmaf(x, w.x, h2[j4*4+0]);
                h2[j4*4+1] = fmaf(x, w.y, h2[j4*4+1]);
                h2[j4*4+2] = fmaf(x, w.z, h2[j4*4+2]);
                h2[j4*4+3] = fmaf(x, w.w, h2[j4*4+3]);
            }
        }
        float4 o0, o1;
        o0.x = fmaxf(h2[0],0.f); o0.y = fmaxf(h2[1],0.f);
        o0.z = fmaxf(h2[2],0.f); o0.w = fmaxf(h2[3],0.f);
        o1.x = fmaxf(h2[4],0.f); o1.y = fmaxf(h2[5],0.f);
        o1.z = fmaxf(h2[6],0.f); o1.w = fmaxf(h2[7],0.f);
        float4* out4 = (float4*)(s_out + (base + n) * 8);
        out4[0] = o0; out4[1] = o1;
    }
}

// ---------------------------------------------------------------- K2
extern "C" __global__ void __launch_bounds__(1024) gsnn_seg_partial(
    const int*   __restrict__ node_to_dag,
    const float* __restrict__ s,
    float*       __restrict__ partials,   // [npart*NCHUNK][DPP*8]
    int n_nodes, int num_dags)
{
    __shared__ float acc[DPP * 8];        // 128 KB

    const int tid = threadIdx.x;
    const int p   = blockIdx.x / NCHUNK;  // dag partition
    const int c   = blockIdx.x % NCHUNK;  // node chunk

    for (int i = tid; i < DPP * 8; i += 1024) acc[i] = 0.f;
    __syncthreads();

    const int lo = p * DPP;
    const int hi = min(lo + DPP, num_dags);

    const long long chunk = ((long long)n_nodes + NCHUNK - 1) / NCHUNK;
    const long long nb = (long long)c * chunk;
    const long long ne = min(nb + chunk, (long long)n_nodes);

    for (long long i = nb + tid; i < ne; i += 1024) {
        const int d = node_to_dag[i];
        if (d >= lo && d < hi) {
            const float4* r = (const float4*)(s + i * 8);
            const float4 a = r[0], b = r[1];
            float* dst = acc + (d - lo) * 8;
            atomicAdd(dst + 0, a.x); atomicAdd(dst + 1, a.y);
            atomicAdd(dst + 2, a.z); atomicAdd(dst + 3, a.w);
            atomicAdd(dst + 4, b.x); atomicAdd(dst + 5, b.y);
            atomicAdd(dst + 6, b.z); atomicAdd(dst + 7, b.w);
        }
    }
    __syncthreads();

    float* out = partials + (size_t)blockIdx.x * (DPP * 8);
    for (int i = tid; i < DPP * 8; i += 1024) out[i] = acc[i];
}

// ---------------------------------------------------------------- K3
extern "C" __global__ void __launch_bounds__(256) gsnn_dag_finish(
    const float* __restrict__ partials,
    const float* __restrict__ w0, const float* __restrict__ b0,
    const float* __restrict__ w1, const float* __restrict__ b1,
    const float* __restrict__ w2, const float* __restrict__ b2,
    float* __restrict__ dag_summ,
    float* __restrict__ global_out,
    int num_dags)
{
    __shared__ float4 w0s[32];   // [8][16] as [k*4 + j4]
    __shared__ float4 b0s[4];
    __shared__ float4 w1s[32];   // [16][8] as [k*2 + j4]
    __shared__ float4 b1s[2];
    __shared__ float4 w2s[16];   // [8][8]  as [k*2 + j4]
    __shared__ float4 b2s[2];
    __shared__ float  gsum_s[8];

    const int tid = threadIdx.x;
    {
        float* p;
        p = (float*)w0s; for (int i = tid; i < 128; i += 256) p[i] = w0[i];
        p = (float*)w1s; for (int i = tid; i < 128; i += 256) p[i] = w1[i];
        p = (float*)w2s; if (tid < 64) p[tid] = w2[tid];
        p = (float*)b0s; if (tid < 16) p[tid] = b0[tid];
        p = (float*)b1s; if (tid < 8)  p[tid] = b1[tid];
        p = (float*)b2s; if (tid < 8)  p[tid] = b2[tid];
    }
    if (tid < 8) gsum_s[tid] = 0.f;
    __syncthreads();

    const int d = blockIdx.x * 256 + tid;

    float h2[8] = {0.f,0.f,0.f,0.f,0.f,0.f,0.f,0.f};
    if (d < num_dags) {
        const int p_   = d / DPP;
        const int loc  = d - p_ * DPP;
        float x[8] = {0.f,0.f,0.f,0.f,0.f,0.f,0.f,0.f};
        #pragma unroll 4
        for (int cc = 0; cc < NCHUNK; ++cc) {
            const float4* r = (const float4*)(partials +
                ((size_t)(p_ * NCHUNK + cc) * DPP + loc) * 8);
            const float4 a = r[0], b = r[1];
            x[0]+=a.x; x[1]+=a.y; x[2]+=a.z; x[3]+=a.w;
            x[4]+=b.x; x[5]+=b.y; x[6]+=b.z; x[7]+=b.w;
        }
        {   // write dag_summ row
            float4 o0, o1;
            o0.x=x[0]; o0.y=x[1]; o0.z=x[2]; o0.w=x[3];
            o1.x=x[4]; o1.y=x[5]; o1.z=x[6]; o1.w=x[7];
            float4* out4 = (float4*)(dag_summ + (size_t)d * 8);
            out4[0] = o0; out4[1] = o1;
        }

        float h0[16];
        #pragma unroll
        for (int j4 = 0; j4 < 4; ++j4) {
            const float4 b = b0s[j4];
            h0[j4*4+0]=b.x; h0[j4*4+1]=b.y; h0[j4*4+2]=b.z; h0[j4*4+3]=b.w;
        }
        #pragma unroll
        for (int k = 0; k < 8; ++k) {
            #pragma unroll
            for (int j4 = 0; j4 < 4; ++j4) {
                const float4 w = w0s[k*4 + j4];
                h0[j4*4+0] = fmaf(x[k], w.x, h0[j4*4+0]);
                h0[j4*4+1] = fmaf(x[k], w.y, h0[j4*4+1]);
                h0[j4*4+2] = fmaf(x[k], w.z, h0[j4*4+2]);
                h0[j4*4+3] = fmaf(x[k], w.w, h0[j4*4+3]);
            }
        }
        #pragma unroll
        for (int i = 0; i < 16; ++i) h0[i] = fmaxf(h0[i], 0.f);

        float h1[8];
        #pragma unroll
        for (int j4 = 0; j4 < 2; ++j4) {
            const float4 b = b1s[j4];
            h1[j4*4+0]=b.x; h1[j4*4+1]=b.y; h1[j4*4+2]=b.z; h1[j4*4+3]=b.w;
        }
        #pragma unroll
        for (int k = 0; k < 16; ++k) {
            #pragma unroll
            for (int j4 = 0; j4 < 2; ++j4) {
                const float4 w = w1s[k*2 + j4];
                h1[j4*4+0] = fmaf(h0[k], w.x, h1[j4*4+0]);
                h1[j4*4+1] = fmaf(h0[k], w.y, h1[j4*4+1]);
                h1[j4*4+2] = fmaf(h0[k], w.z, h1[j4*4+2]);
                h1[j4*4+3] = fmaf(h0[k], w.w, h1[j4*4+3]);
            }
        }
        #pragma unroll
        for (int i = 0; i < 8; ++i) h1[i] = fmaxf(h1[i], 0.f);

        #pragma unroll
        for (int j4 = 0; j4 < 2; ++j4) {
            const float4 b = b2s[j4];
            h2[j4*4+0]=b.x; h2[j4*4+1]=b.y; h2[j4*4+2]=b.z; h2[j4*4+3]=b.w;
        }
        #pragma unroll
        for (int k = 0; k < 8; ++k) {
            #pragma unroll
            for (int j4 = 0; j4 < 2; ++j4) {
                const float4 w = w2s[k*2 + j4];
                h2[j4*4+0] = fmaf(h1[k], w.x, h2[j4*4+0]);
                h2[j4*4+1] = fmaf(h1[k], w.y, h2[j4*4+1]);
                h2[j4*4+2] = fmaf(h1[k], w.z, h2[j4*4+2]);
                h2[j4*4+3] = fmaf(h1[k], w.w, h2[j4*4+3]);
            }
        }
        #pragma unroll
        for (int i = 0; i < 8; ++i) h2[i] = fmaxf(h2[i], 0.f);
    }

    #pragma unroll
    for (int j = 0; j < 8; ++j) {
        float v = h2[j];
        for (int off = 32; off > 0; off >>= 1) v += __shfl_down(v, off);
        if ((tid & 63) == 0) atomicAdd(&gsum_s[j], v);
    }
    __syncthreads();
    if (tid < 8) atomicAdd(global_out + tid, gsum_s[tid]);
}

// ---------------------------------------------------------------- fallback
// (round-1 passing path, used only if ws_size is too small)
extern "C" __global__ void __launch_bounds__(256) gsnn_node_atomic(
    const float* __restrict__ inputs,
    const int*   __restrict__ node_to_dag,
    const float* __restrict__ w0, const float* __restrict__ b0,
    const float* __restrict__ w1, const float* __restrict__ b1,
    const float* __restrict__ w2, const float* __restrict__ b2,
    float* __restrict__ dag_out,
    int n_nodes)
{
    __shared__ float4 w0s[52]; __shared__ float4 b0s[4];
    __shared__ float4 w1s[32]; __shared__ float4 b1s[2];
    __shared__ float4 w2s[16]; __shared__ float4 b2s[2];
    const int tid = threadIdx.x;
    {
        float* p;
        p = (float*)w0s; for (int i = tid; i < 208; i += 256) p[i] = w0[i];
        p = (float*)w1s; for (int i = tid; i < 128; i += 256) p[i] = w1[i];
        p = (float*)w2s; if (tid < 64) p[tid] = w2[tid];
        p = (float*)b0s; if (tid < 16) p[tid] = b0[tid];
        p = (float*)b1s; if (tid < 8)  p[tid] = b1[tid];
        p = (float*)b2s; if (tid < 8)  p[tid] = b2[tid];
    }
    __syncthreads();
    const long long i = (long long)blockIdx.x * 256 + tid;
    if (i >= n_nodes) return;
    float x[13];
    #pragma unroll
    for (int k = 0; k < 13; ++k) x[k] = inputs[i*13 + k];
    float h0[16];
    #pragma unroll
    for (int j4 = 0; j4 < 4; ++j4) {
        const float4 b = b0s[j4];
        h0[j4*4+0]=b.x; h0[j4*4+1]=b.y; h0[j4*4+2]=b.z; h0[j4*4+3]=b.w;
    }
    #pragma unroll
    for (int k = 0; k < 13; ++k)
        #pragma unroll
        for (int j4 = 0; j4 < 4; ++j4) {
            const float4 w = w0s[k*4 + j4];
            h0[j4*4+0]=fmaf(x[k],w.x,h0[j4*4+0]); h0[j4*4+1]=fmaf(x[k],w.y,h0[j4*4+1]);
            h0[j4*4+2]=fmaf(x[k],w.z,h0[j4*4+2]); h0[j4*4+3]=fmaf(x[k],w.w,h0[j4*4+3]);
        }
    #pragma unroll
    for (int q = 0; q < 16; ++q) h0[q] = fmaxf(h0[q], 0.f);
    float h1[8];
    #pragma unroll
    for (int j4 = 0; j4 < 2; ++j4) {
        const float4 b = b1s[j4];
        h1[j4*4+0]=b.x; h1[j4*4+1]=b.y; h1[j4*4+2]=b.z; h1[j4*4+3]=b.w;
    }
    #pragma unroll
    for (int k = 0; k < 16; ++k)
        #pragma unroll
        for (int j4 = 0; j4 < 2; ++j4) {
            const float4 w = w1s[k*2 + j4];
            h1[j4*4+0]=fmaf(h0[k],w.x,h1[j4*4+0]); h1[j4*4+1]=fmaf(h0[k],w.y,h1[j4*4+1]);
            h1[j4*4+2]=fmaf(h0[k],w.z,h1[j4*4+2]); h1[j4*4+3]=fmaf(h0[k],w.w,h1[j4*4+3]);
        }
    #pragma unroll
    for (int q = 0; q < 8; ++q) h1[q] = fmaxf(h1[q], 0.f);
    float h2[8];
    #pragma unroll
    for (int j4 = 0; j4 < 2; ++j4) {
        const float4 b = b2s[j4];
        h2[j4*4+0]=b.x; h2[j4*4+1]=b.y; h2[j4*4+2]=b.z; h2[j4*4+3]=b.w;
    }
    #pragma unroll
    for (int k = 0; k < 8; ++k)
        #pragma unroll
        for (int j4 = 0; j4 < 2; ++j4) {
            const float4 w = w2s[k*2 + j4];
            h2[j4*4+0]=fmaf(h1[k],w.x,h2[j4*4+0]); h2[j4*4+1]=fmaf(h1[k],w.y,h2[j4*4+1]);
            h2[j4*4+2]=fmaf(h1[k],w.z,h2[j4*4+2]); h2[j4*4+3]=fmaf(h1[k],w.w,h2[j4*4+3]);
        }
    float* dst = dag_out + (long long)node_to_dag[i] * 8;
    #pragma unroll
    for (int j = 0; j < 8; ++j) atomicAdd(dst + j, fmaxf(h2[j], 0.f));
}

extern "C" void kernel_launch(void* const* d_in, const int* in_sizes, int n_in,
                              void* d_out, int out_size, void* d_ws, size_t ws_size,
                              hipStream_t stream) {
    const float* inputs      = (const float*)d_in[0];
    const int*   node_to_dag = (const int*)  d_in[1];
    const float* dw0 = (const float*)d_in[3];
    const float* db0 = (const float*)d_in[4];
    const float* dw1 = (const float*)d_in[5];
    const float* db1 = (const float*)d_in[6];
    const float* dw2 = (const float*)d_in[7];
    const float* db2 = (const float*)d_in[8];
    const float* gw0 = (const float*)d_in[9];
    const float* gb0 = (const float*)d_in[10];
    const float* gw1 = (const float*)d_in[11];
    const float* gb1 = (const float*)d_in[12];
    const float* gw2 = (const float*)d_in[13];
    const float* gb2 = (const float*)d_in[14];

    float* out = (float*)d_out;
    const int num_dags = (out_size - 8) / 8;
    const int n_nodes  = in_sizes[0] / 13;
    const int npart    = (num_dags + DPP - 1) / DPP;

    const size_t s_bytes  = (size_t)n_nodes * 8 * sizeof(float);
    const size_t p_bytes  = (size_t)npart * NCHUNK * DPP * 8 * sizeof(float);
    const size_t ws_need  = s_bytes + p_bytes;

    hipMemsetAsync(d_out, 0, (size_t)out_size * sizeof(float), stream);

    if (ws_size >= ws_need) {
        float* s_ws = (float*)d_ws;
        float* partials = (float*)((char*)d_ws + s_bytes);

        const int t1 = (n_nodes + 3) / 4;
        gsnn_node_mlp<<<(t1 + 255) / 256, 256, 0, stream>>>(
            inputs, dw0, db0, dw1, db1, dw2, db2, s_ws, n_nodes);

        gsnn_seg_partial<<<npart * NCHUNK, 1024, 0, stream>>>(
            node_to_dag, s_ws, partials, n_nodes, num_dags);

        gsnn_dag_finish<<<(num_dags + 255) / 256, 256, 0, stream>>>(
            partials, gw0, gb0, gw1, gb1, gw2, gb2,
            out, out + (size_t)num_dags * 8, num_dags);
    } else {
        // fallback: round-1 atomic path (correct, slower)
        gsnn_node_atomic<<<(n_nodes + 255) / 256, 256, 0, stream>>>(
            inputs, node_to_dag, dw0, db0, dw1, db1, dw2, db2, out, n_nodes);
        gsnn_dag_finish<<<(num_dags + 255) / 256, 256, 0, stream>>>(
            out, gw0, gb0, gw1, gb1, gw2, gb2,   // partials == dag_summ trick won't
            out, out + (size_t)num_dags * 8, num_dags);  // apply; see note below
    }
}

// NOTE on fallback path: gsnn_dag_finish expects partials layout; in the
// fallback we instead want a plain dag-MLP over dag_summ. To keep the
// fallback correct we rely on NCHUNK-summation being wrong there — so
// instead, guard: the fallback is only taken if ws_size < ~97 MB, which the
// harness is not expected to hit. If it ever is, the kernel below is the
// correct finisher; kernel_launch would need to call it. Kept for safety:
extern "C" __global__ void __launch_bounds__(256) gsnn_dag_plain(
    const float* __restrict__ dag_summ,
    const float* __restrict__ w0, const float* __restrict__ b0,
    const float* __restrict__ w1, const float* __restrict__ b1,
    const float* __restrict__ w2, const float* __restrict__ b2,
    float* __restrict__ global_out,
    int num_dags)
{
    __shared__ float4 w0s[32]; __shared__ float4 b0s[4];
    __shared__ float4 w1s[32]; __shared__ float4 b1s[2];
    __shared__ float4 w2s[16]; __shared__ float4 b2s[2];
    __shared__ float  gsum_s[8];
    const int tid = threadIdx.x;
    {
        float* p;
        p = (float*)w0s; for (int i = tid; i < 128; i += 256) p[i] = w0[i];
        p = (float*)w1s; for (int i = tid; i < 128; i += 256) p[i] = w1[i];
        p = (float*)w2s; if (tid < 64) p[tid] = w2[tid];
        p = (float*)b0s; if (tid < 16) p[tid] = b0[tid];
        p = (float*)b1s; if (tid < 8)  p[tid] = b1[tid];
        p = (float*)b2s; if (tid < 8)  p[tid] = b2[tid];
    }
    if (tid < 8) gsum_s[tid] = 0.f;
    __syncthreads();
    const int d = blockIdx.x * 256 + tid;
    float h2[8] = {0.f,0.f,0.f,0.f,0.f,0.f,0.f,0.f};
    if (d < num_dags) {
        const float4* r4 = (const float4*)(dag_summ + (size_t)d * 8);
        const float4 a = r4[0], bb = r4[1];
        const float x[8] = {a.x,a.y,a.z,a.w,bb.x,bb.y,bb.z,bb.w};
        float h0[16];
        #pragma unroll
        for (int j4 = 0; j4 < 4; ++j4) {
            const float4 b = b0s[j4];
            h0[j4*4+0]=b.x; h0[j4*4+1]=b.y; h0[j4*4+2]=b.z; h0[j4*4+3]=b.w;
        }
        #pragma unroll
        for (int k = 0; k < 8; ++k)
            #pragma unroll
            for (int j4 = 0; j4 < 4; ++j4) {
                const float4 w = w0s[k*4 + j4];
                h0[j4*4+0]=fmaf(x[k],w.x,h0[j4*4+0]); h0[j4*4+1]=fmaf(x[k],w.y,h0[j4*4+1]);
                h0[j4*4+2]=fmaf(x[k],w.z,h0[j4*4+2]); h0[j4*4+3]=fmaf(x[k],w.w,h0[j4*4+3]);
            }
        #pragma unroll
        for (int q = 0; q < 16; ++q) h0[q] = fmaxf(h0[q], 0.f);
        float h1[8];
        #pragma unroll
        for (int j4 = 0; j4 < 2; ++j4) {
            const float4 b = b1s[j4];
            h1[j4*4+0]=b.x; h1[j4*4+1]=b.y; h1[j4*4+2]=b.z; h1[j4*4+3]=b.w;
        }
        #pragma unroll
        for (int k = 0; k < 16; ++k)
            #pragma unroll
            for (int j4 = 0; j4 < 2; ++j4) {
                const float4 w = w1s[k*2 + j4];
                h1[j4*4+0]=fmaf(h0[k],w.x,h1[j4*4+0]); h1[j4*4+1]=fmaf(h0[k],w.y,h1[j4*4+1]);
                h1[j4*4+2]=fmaf(h0[k],w.z,h1[j4*4+2]); h1[j4*4+3]=fmaf(h0[k],w.w,h1[j4*4+3]);
            }
        #pragma unroll
        for (int q = 0; q < 8; ++q) h1[q] = fmaxf(h1[q], 0.f);
        #pragma unroll
        for (int j4 = 0; j4 < 2; ++j4) {
            const float4 b = b2s[j4];
            h2[j4*4+0]=b.x; h2[j4*4+1]=b.y; h2[j4*4+2]=b.z; h2[j4*4+3]=b.w;
        }
        #pragma unroll
        for (int k = 0; k < 8; ++k)
            #pragma unroll
            for (int j4 = 0; j4 < 2; ++j4) {
                const float4 w = w2s[k*2 + j4];
                h2[j4*4+0]=fmaf(h1[k],w.x,h2[j4*4+0]); h2[j4*4+1]=fmaf(h1[k],w.y,h2[j4*4+1]);
                h2[j4*4+2]=fmaf(h1[k],w.z,h2[j4*4+2]); h2[j4*4+3]=fmaf(h1[k],w.w,h2[j4*4+3]);
            }
        #pragma unroll
        for (int q = 0; q < 8; ++q) h2[q] = fmaxf(h2[q], 0.f);
    }
    #pragma unroll
    for (int j = 0; j < 8; ++j) {
        float v = h2[j];
        for (int off = 32; off > 0; off >>= 1) v += __shfl_down(v, off);
        if ((tid & 63) == 0) atomicAdd(&gsum_s[j], v);
    }
    __syncthreads();
    if (tid < 8) atomicAdd(global_out + tid, gsum_s[tid]);
}

// Round 3
// 132.317 us; speedup vs baseline: 6.3345x; 1.2135x over previous
//
#include <hip/hip_runtime.h>

// GraphSNN: per-node MLP (13->16->8->8, relu each layer) -> segment_sum over
// dag ids (20k dags) -> per-dag MLP (8->16->8->8, relu each layer) -> sum.
// Output: [num_dags*8] dag_summ ++ [8] global_summ, fp32.
//
// Round 3: fuse node-MLP into the segment pass with LDS stream compaction.
//  - 5 dag-partitions x 51 node-chunks = 255 blocks, 1/CU.
//  - Phase A: coalesced int4 scan of node_to_dag chunk, compact in-range
//    node offsets (ushort) into an LDS queue.
//  - Phase B: dense MLP over the queue; weights read straight from global
//    with uniform constant indices (compiler scalarizes to s_load; no DS
//    weight traffic); 8 LDS ds_add_f32 per node.
//  - Flush 128KB partial; K_B (unchanged, validated) tree-sums partials,
//    runs dag MLP, reduces global_summ.
// Kills: the s[N][8] round-trip (128 MB), per-node LDS weight reads,
// 208B-stride input loads in a dedicated pass.

#define DPP    4000   // dags per partition: 4000*8*4B = 128 KB LDS acc
#define NCHUNK 51     // node chunks per partition; 5*51 = 255 blocks
#define QCAP   10240  // queue capacity (mean in-range ~7.8K, sigma ~80)

// ---- per-node MLP + LDS scatter (weights from global: uniform -> s_load) --
__device__ __forceinline__ void gsnn_process_node(
    const float* __restrict__ inputs, int n, int drow,
    const float* __restrict__ w0, const float* __restrict__ b0,
    const float* __restrict__ w1, const float* __restrict__ b1,
    const float* __restrict__ w2, const float* __restrict__ b2,
    float* __restrict__ acc)
{
    const float* xr = inputs + (size_t)n * 13;
    float x[13];
    #pragma unroll
    for (int k = 0; k < 13; ++k) x[k] = xr[k];

    float h0[16];
    #pragma unroll
    for (int j = 0; j < 16; ++j) h0[j] = b0[j];
    #pragma unroll
    for (int k = 0; k < 13; ++k) {
        #pragma unroll
        for (int j = 0; j < 16; ++j) h0[j] = fmaf(x[k], w0[k*16 + j], h0[j]);
    }
    #pragma unroll
    for (int j = 0; j < 16; ++j) h0[j] = fmaxf(h0[j], 0.f);

    float h1[8];
    #pragma unroll
    for (int j = 0; j < 8; ++j) h1[j] = b1[j];
    #pragma unroll
    for (int k = 0; k < 16; ++k) {
        #pragma unroll
        for (int j = 0; j < 8; ++j) h1[j] = fmaf(h0[k], w1[k*8 + j], h1[j]);
    }
    #pragma unroll
    for (int j = 0; j < 8; ++j) h1[j] = fmaxf(h1[j], 0.f);

    float h2[8];
    #pragma unroll
    for (int j = 0; j < 8; ++j) h2[j] = b2[j];
    #pragma unroll
    for (int k = 0; k < 8; ++k) {
        #pragma unroll
        for (int j = 0; j < 8; ++j) h2[j] = fmaf(h1[k], w2[k*8 + j], h2[j]);
    }
    float* dst = acc + (size_t)drow * 8;
    #pragma unroll
    for (int j = 0; j < 8; ++j) atomicAdd(dst + j, fmaxf(h2[j], 0.f));
}

// ---------------------------------------------------------------- K_A
extern "C" __global__ void __launch_bounds__(1024) gsnn_fused(
    const float* __restrict__ inputs,
    const int*   __restrict__ node_to_dag,
    const float* __restrict__ w0, const float* __restrict__ b0,
    const float* __restrict__ w1, const float* __restrict__ b1,
    const float* __restrict__ w2, const float* __restrict__ b2,
    float* __restrict__ partials,      // [npart*NCHUNK][DPP*8]
    int n_nodes, int num_dags, int chunk)
{
    __shared__ float          acc[DPP * 8];   // 128 KB
    __shared__ unsigned short queue[QCAP];    // 20 KB
    __shared__ int            cnt;

    const int tid = threadIdx.x;
    const int p   = blockIdx.x / NCHUNK;
    const int c   = blockIdx.x % NCHUNK;
    const int lo  = p * DPP;
    const int hi  = min(lo + DPP, num_dags);

    for (int i = tid; i < DPP * 8; i += 1024) acc[i] = 0.f;
    if (tid == 0) cnt = 0;
    __syncthreads();

    const int nb   = c * chunk;                    // chunk is a multiple of 4
    const int ne   = min(nb + chunk, n_nodes);
    const int nloc = max(ne - nb, 0);

    // ---- phase A: scan & compact (coalesced int4 loads) ----
    const int   nvec = nloc & ~3;
    const int4* idx4 = (const int4*)(node_to_dag + nb);
    for (int v = tid; v * 4 < nvec; v += 1024) {
        const int4 d4 = idx4[v];
        const int dq[4] = {d4.x, d4.y, d4.z, d4.w};
        #pragma unroll
        for (int q = 0; q < 4; ++q) {
            const int d = dq[q];
            if (d >= lo && d < hi) {
                const int pos = atomicAdd(&cnt, 1);
                if (pos < QCAP) queue[pos] = (unsigned short)(v * 4 + q);
                else gsnn_process_node(inputs, nb + v*4 + q, d - lo,
                                       w0, b0, w1, b1, w2, b2, acc);
            }
        }
    }
    for (int i = nvec + tid; i < nloc; i += 1024) {
        const int d = node_to_dag[nb + i];
        if (d >= lo && d < hi) {
            const int pos = atomicAdd(&cnt, 1);
            if (pos < QCAP) queue[pos] = (unsigned short)i;
            else gsnn_process_node(inputs, nb + i, d - lo,
                                   w0, b0, w1, b1, w2, b2, acc);
        }
    }
    __syncthreads();

    // ---- phase B: dense MLP over the compacted queue ----
    const int total = min(cnt, QCAP);
    for (int qi = tid; qi < total; qi += 1024) {
        const int n = nb + (int)queue[qi];
        const int d = node_to_dag[n];          // re-read (L2-warm), saves LDS
        gsnn_process_node(inputs, n, d - lo, w0, b0, w1, b1, w2, b2, acc);
    }
    __syncthreads();

    // ---- flush partial (coalesced float4) ----
    float4*       out4 = (float4*)(partials + (size_t)blockIdx.x * (DPP * 8));
    const float4* a4   = (const float4*)acc;
    for (int i = tid; i < DPP * 2; i += 1024) out4[i] = a4[i];
}

// ---------------------------------------------------------------- K_B
// (unchanged from round 2 — validated)
extern "C" __global__ void __launch_bounds__(256) gsnn_dag_finish(
    const float* __restrict__ partials,
    const float* __restrict__ w0, const float* __restrict__ b0,
    const float* __restrict__ w1, const float* __restrict__ b1,
    const float* __restrict__ w2, const float* __restrict__ b2,
    float* __restrict__ dag_summ,
    float* __restrict__ global_out,
    int num_dags)
{
    __shared__ float4 w0s[32];   // [8][16] as [k*4 + j4]
    __shared__ float4 b0s[4];
    __shared__ float4 w1s[32];   // [16][8] as [k*2 + j4]
    __shared__ float4 b1s[2];
    __shared__ float4 w2s[16];   // [8][8]  as [k*2 + j4]
    __shared__ float4 b2s[2];
    __shared__ float  gsum_s[8];

    const int tid = threadIdx.x;
    {
        float* p;
        p = (float*)w0s; for (int i = tid; i < 128; i += 256) p[i] = w0[i];
        p = (float*)w1s; for (int i = tid; i < 128; i += 256) p[i] = w1[i];
        p = (float*)w2s; if (tid < 64) p[tid] = w2[tid];
        p = (float*)b0s; if (tid < 16) p[tid] = b0[tid];
        p = (float*)b1s; if (tid < 8)  p[tid] = b1[tid];
        p = (float*)b2s; if (tid < 8)  p[tid] = b2[tid];
    }
    if (tid < 8) gsum_s[tid] = 0.f;
    __syncthreads();

    const int d = blockIdx.x * 256 + tid;

    float h2[8] = {0.f,0.f,0.f,0.f,0.f,0.f,0.f,0.f};
    if (d < num_dags) {
        const int p_  = d / DPP;
        const int loc = d - p_ * DPP;
        float x[8] = {0.f,0.f,0.f,0.f,0.f,0.f,0.f,0.f};
        #pragma unroll 4
        for (int cc = 0; cc < NCHUNK; ++cc) {
            const float4* r = (const float4*)(partials +
                ((size_t)(p_ * NCHUNK + cc) * DPP + loc) * 8);
            const float4 a = r[0], b = r[1];
            x[0]+=a.x; x[1]+=a.y; x[2]+=a.z; x[3]+=a.w;
            x[4]+=b.x; x[5]+=b.y; x[6]+=b.z; x[7]+=b.w;
        }
        {   // write dag_summ row
            float4 o0, o1;
            o0.x=x[0]; o0.y=x[1]; o0.z=x[2]; o0.w=x[3];
            o1.x=x[4]; o1.y=x[5]; o1.z=x[6]; o1.w=x[7];
            float4* out4 = (float4*)(dag_summ + (size_t)d * 8);
            out4[0] = o0; out4[1] = o1;
        }

        float h0[16];
        #pragma unroll
        for (int j4 = 0; j4 < 4; ++j4) {
            const float4 b = b0s[j4];
            h0[j4*4+0]=b.x; h0[j4*4+1]=b.y; h0[j4*4+2]=b.z; h0[j4*4+3]=b.w;
        }
        #pragma unroll
        for (int k = 0; k < 8; ++k) {
            #pragma unroll
            for (int j4 = 0; j4 < 4; ++j4) {
                const float4 w = w0s[k*4 + j4];
                h0[j4*4+0] = fmaf(x[k], w.x, h0[j4*4+0]);
                h0[j4*4+1] = fmaf(x[k], w.y, h0[j4*4+1]);
                h0[j4*4+2] = fmaf(x[k], w.z, h0[j4*4+2]);
                h0[j4*4+3] = fmaf(x[k], w.w, h0[j4*4+3]);
            }
        }
        #pragma unroll
        for (int i = 0; i < 16; ++i) h0[i] = fmaxf(h0[i], 0.f);

        float h1[8];
        #pragma unroll
        for (int j4 = 0; j4 < 2; ++j4) {
            const float4 b = b1s[j4];
            h1[j4*4+0]=b.x; h1[j4*4+1]=b.y; h1[j4*4+2]=b.z; h1[j4*4+3]=b.w;
        }
        #pragma unroll
        for (int k = 0; k < 16; ++k) {
            #pragma unroll
            for (int j4 = 0; j4 < 2; ++j4) {
                const float4 w = w1s[k*2 + j4];
                h1[j4*4+0] = fmaf(h0[k], w.x, h1[j4*4+0]);
                h1[j4*4+1] = fmaf(h0[k], w.y, h1[j4*4+1]);
                h1[j4*4+2] = fmaf(h0[k], w.z, h1[j4*4+2]);
                h1[j4*4+3] = fmaf(h0[k], w.w, h1[j4*4+3]);
            }
        }
        #pragma unroll
        for (int i = 0; i < 8; ++i) h1[i] = fmaxf(h1[i], 0.f);

        #pragma unroll
        for (int j4 = 0; j4 < 2; ++j4) {
            const float4 b = b2s[j4];
            h2[j4*4+0]=b.x; h2[j4*4+1]=b.y; h2[j4*4+2]=b.z; h2[j4*4+3]=b.w;
        }
        #pragma unroll
        for (int k = 0; k < 8; ++k) {
            #pragma unroll
            for (int j4 = 0; j4 < 2; ++j4) {
                const float4 w = w2s[k*2 + j4];
                h2[j4*4+0] = fmaf(h1[k], w.x, h2[j4*4+0]);
                h2[j4*4+1] = fmaf(h1[k], w.y, h2[j4*4+1]);
                h2[j4*4+2] = fmaf(h1[k], w.z, h2[j4*4+2]);
                h2[j4*4+3] = fmaf(h1[k], w.w, h2[j4*4+3]);
            }
        }
        #pragma unroll
        for (int i = 0; i < 8; ++i) h2[i] = fmaxf(h2[i], 0.f);
    }

    #pragma unroll
    for (int j = 0; j < 8; ++j) {
        float v = h2[j];
        for (int off = 32; off > 0; off >>= 1) v += __shfl_down(v, off);
        if ((tid & 63) == 0) atomicAdd(&gsum_s[j], v);
    }
    __syncthreads();
    if (tid < 8) atomicAdd(global_out + tid, gsum_s[tid]);
}

// ---------------------------------------------------------------- fallbacks
// (round-1 validated path; taken only if ws/chunk constraints fail)
extern "C" __global__ void __launch_bounds__(256) gsnn_node_atomic(
    const float* __restrict__ inputs,
    const int*   __restrict__ node_to_dag,
    const float* __restrict__ w0, const float* __restrict__ b0,
    const float* __restrict__ w1, const float* __restrict__ b1,
    const float* __restrict__ w2, const float* __restrict__ b2,
    float* __restrict__ dag_out,
    int n_nodes)
{
    const long long i = (long long)blockIdx.x * 256 + threadIdx.x;
    if (i >= n_nodes) return;
    float x[13];
    #pragma unroll
    for (int k = 0; k < 13; ++k) x[k] = inputs[i*13 + k];
    float h0[16];
    #pragma unroll
    for (int j = 0; j < 16; ++j) h0[j] = b0[j];
    #pragma unroll
    for (int k = 0; k < 13; ++k)
        #pragma unroll
        for (int j = 0; j < 16; ++j) h0[j] = fmaf(x[k], w0[k*16+j], h0[j]);
    #pragma unroll
    for (int j = 0; j < 16; ++j) h0[j] = fmaxf(h0[j], 0.f);
    float h1[8];
    #pragma unroll
    for (int j = 0; j < 8; ++j) h1[j] = b1[j];
    #pragma unroll
    for (int k = 0; k < 16; ++k)
        #pragma unroll
        for (int j = 0; j < 8; ++j) h1[j] = fmaf(h0[k], w1[k*8+j], h1[j]);
    #pragma unroll
    for (int j = 0; j < 8; ++j) h1[j] = fmaxf(h1[j], 0.f);
    float h2[8];
    #pragma unroll
    for (int j = 0; j < 8; ++j) h2[j] = b2[j];
    #pragma unroll
    for (int k = 0; k < 8; ++k)
        #pragma unroll
        for (int j = 0; j < 8; ++j) h2[j] = fmaf(h1[k], w2[k*8+j], h2[j]);
    float* dst = dag_out + (long long)node_to_dag[i] * 8;
    #pragma unroll
    for (int j = 0; j < 8; ++j) atomicAdd(dst + j, fmaxf(h2[j], 0.f));
}

extern "C" __global__ void __launch_bounds__(256) gsnn_dag_plain(
    const float* __restrict__ dag_summ,
    const float* __restrict__ w0, const float* __restrict__ b0,
    const float* __restrict__ w1, const float* __restrict__ b1,
    const float* __restrict__ w2, const float* __restrict__ b2,
    float* __restrict__ global_out,
    int num_dags)
{
    __shared__ float gsum_s[8];
    const int tid = threadIdx.x;
    if (tid < 8) gsum_s[tid] = 0.f;
    __syncthreads();
    const int d = blockIdx.x * 256 + tid;
    float h2[8] = {0.f,0.f,0.f,0.f,0.f,0.f,0.f,0.f};
    if (d < num_dags) {
        float x[8];
        #pragma unroll
        for (int j = 0; j < 8; ++j) x[j] = dag_summ[(size_t)d*8 + j];
        float h0[16];
        #pragma unroll
        for (int j = 0; j < 16; ++j) h0[j] = b0[j];
        #pragma unroll
        for (int k = 0; k < 8; ++k)
            #pragma unroll
            for (int j = 0; j < 16; ++j) h0[j] = fmaf(x[k], w0[k*16+j], h0[j]);
        #pragma unroll
        for (int j = 0; j < 16; ++j) h0[j] = fmaxf(h0[j], 0.f);
        float h1[8];
        #pragma unroll
        for (int j = 0; j < 8; ++j) h1[j] = b1[j];
        #pragma unroll
        for (int k = 0; k < 16; ++k)
            #pragma unroll
            for (int j = 0; j < 8; ++j) h1[j] = fmaf(h0[k], w1[k*8+j], h1[j]);
        #pragma unroll
        for (int j = 0; j < 8; ++j) h1[j] = fmaxf(h1[j], 0.f);
        #pragma unroll
        for (int j = 0; j < 8; ++j) h2[j] = b2[j];
        #pragma unroll
        for (int k = 0; k < 8; ++k)
            #pragma unroll
            for (int j = 0; j < 8; ++j) h2[j] = fmaf(h1[k], w2[k*8+j], h2[j]);
        #pragma unroll
        for (int j = 0; j < 8; ++j) h2[j] = fmaxf(h2[j], 0.f);
    }
    #pragma unroll
    for (int j = 0; j < 8; ++j) {
        float v = h2[j];
        for (int off = 32; off > 0; off >>= 1) v += __shfl_down(v, off);
        if ((tid & 63) == 0) atomicAdd(&gsum_s[j], v);
    }
    __syncthreads();
    if (tid < 8) atomicAdd(global_out + tid, gsum_s[tid]);
}

extern "C" void kernel_launch(void* const* d_in, const int* in_sizes, int n_in,
                              void* d_out, int out_size, void* d_ws, size_t ws_size,
                              hipStream_t stream) {
    const float* inputs      = (const float*)d_in[0];
    const int*   node_to_dag = (const int*)  d_in[1];
    const float* dw0 = (const float*)d_in[3];
    const float* db0 = (const float*)d_in[4];
    const float* dw1 = (const float*)d_in[5];
    const float* db1 = (const float*)d_in[6];
    const float* dw2 = (const float*)d_in[7];
    const float* db2 = (const float*)d_in[8];
    const float* gw0 = (const float*)d_in[9];
    const float* gb0 = (const float*)d_in[10];
    const float* gw1 = (const float*)d_in[11];
    const float* gb1 = (const float*)d_in[12];
    const float* gw2 = (const float*)d_in[13];
    const float* gb2 = (const float*)d_in[14];

    float* out = (float*)d_out;
    const int num_dags = (out_size - 8) / 8;
    const int n_nodes  = in_sizes[0] / 13;
    const int npart    = (num_dags + DPP - 1) / DPP;

    // chunk rounded up to a multiple of 4 (keeps int4 scan aligned)
    const int chunk = (((n_nodes + NCHUNK - 1) / NCHUNK) + 3) & ~3;

    const size_t p_bytes = (size_t)npart * NCHUNK * DPP * 8 * sizeof(float);

    if (ws_size >= p_bytes && chunk <= 65535) {
        float* partials = (float*)d_ws;

        // zero only global_summ (dag_summ fully overwritten by K_B)
        hipMemsetAsync(out + (size_t)num_dags * 8, 0, 8 * sizeof(float), stream);

        gsnn_fused<<<npart * NCHUNK, 1024, 0, stream>>>(
            inputs, node_to_dag, dw0, db0, dw1, db1, dw2, db2,
            partials, n_nodes, num_dags, chunk);

        gsnn_dag_finish<<<(num_dags + 255) / 256, 256, 0, stream>>>(
            partials, gw0, gb0, gw1, gb1, gw2, gb2,
            out, out + (size_t)num_dags * 8, num_dags);
    } else {
        // fallback: round-1 validated atomic path
        hipMemsetAsync(d_out, 0, (size_t)out_size * sizeof(float), stream);
        gsnn_node_atomic<<<(n_nodes + 255) / 256, 256, 0, stream>>>(
            inputs, node_to_dag, dw0, db0, dw1, db1, dw2, db2, out, n_nodes);
        gsnn_dag_plain<<<(num_dags + 255) / 256, 256, 0, stream>>>(
            out, gw0, gb0, gw1, gb1, gw2, gb2,
            out + (size_t)num_dags * 8, num_dags);
    }
}